// Round 13
// baseline (1643.004 us; speedup 1.0000x reference)
//
#include <hip/hip_runtime.h>

typedef unsigned short ushort_t;
typedef __bf16 bf16x8 __attribute__((ext_vector_type(8)));
typedef float f32x4 __attribute__((ext_vector_type(4)));

// sizes (fixed by the problem)
#define NB 8
#define BB 2
#define TT 2048
#define DD 2048
#define FF 8192
#define MM (BB * TT)          // 4096 rows
#define BTD ((size_t)BB * TT * DD)   // 8388608

__device__ __forceinline__ unsigned short f2bf(float f) {
  unsigned int u = __float_as_uint(f);
  u += 0x7FFFu + ((u >> 16) & 1u);
  return (unsigned short)(u >> 16);
}

__device__ __forceinline__ float gelu_tanh(float x) {
  float u = 0.7978845608028654f * (x + 0.044715f * x * x * x);
  float e = __expf(2.0f * u);
  float th = 1.0f - 2.0f / (e + 1.0f);   // robust tanh(u), e=inf -> 1
  return 0.5f * x * (1.0f + th);
}

template <int N>
__device__ __forceinline__ void wait_vmcnt() {
  if constexpr (N == 0) asm volatile("s_waitcnt vmcnt(0)" ::: "memory");
  else if constexpr (N == 3) asm volatile("s_waitcnt vmcnt(3)" ::: "memory");
  else if constexpr (N == 4) asm volatile("s_waitcnt vmcnt(4)" ::: "memory");
}

#define ASYNC_COPY16(gp, lp)                                                   \
  __builtin_amdgcn_global_load_lds(                                            \
      (__attribute__((address_space(1))) void*)(gp),                           \
      (__attribute__((address_space(3))) void*)(lp), 16, 0, 0)

// ---------------------------------------------------------------------------
// fp32 (R x C) -> bf16 transposed (C x R).  float4 in, ushort4 out (G13).
__global__ __launch_bounds__(256) void transpose_conv(
    const float* __restrict__ in, ushort_t* __restrict__ out, int R, int C) {
  __shared__ float tile[32][33];
  const int tx = threadIdx.x & 7;   // 8 x float4 = 32 cols
  const int ty = threadIdx.x >> 3;  // 32 rows
  const int r0 = blockIdx.y * 32, c0 = blockIdx.x * 32;
  float4 v = *(const float4*)(in + (size_t)(r0 + ty) * C + c0 + tx * 4);
  tile[ty][tx * 4 + 0] = v.x;
  tile[ty][tx * 4 + 1] = v.y;
  tile[ty][tx * 4 + 2] = v.z;
  tile[ty][tx * 4 + 3] = v.w;
  __syncthreads();
  ushort4 o;
  o.x = f2bf(tile[tx * 4 + 0][ty]);
  o.y = f2bf(tile[tx * 4 + 1][ty]);
  o.z = f2bf(tile[tx * 4 + 2][ty]);
  o.w = f2bf(tile[tx * 4 + 3][ty]);
  *(ushort4*)(out + (size_t)(c0 + ty) * R + r0 + tx * 4) = o;
}

// ---------------------------------------------------------------------------
// Fused block-attention: ONE PASS over V (V rows held in registers).
__global__ __launch_bounds__(256) void attn_fuse(
    const float* __restrict__ blocks, const float* __restrict__ partial,
    const float* __restrict__ proj_w, const float* __restrict__ norm_scale,
    float* __restrict__ h_out, ushort_t* __restrict__ h_bf) {
  const int t = threadIdx.x;
  const int bt = blockIdx.x;
  const size_t rowoff = (size_t)bt * DD;
  const int d0 = t * 4;

  float w[8];
  {
    float4 ns = *(const float4*)(norm_scale + d0);
    float4 pw = *(const float4*)(proj_w + d0);
    w[0] = ns.x * pw.x; w[1] = ns.y * pw.y; w[2] = ns.z * pw.z; w[3] = ns.w * pw.w;
    ns = *(const float4*)(norm_scale + 1024 + d0);
    pw = *(const float4*)(proj_w + 1024 + d0);
    w[4] = ns.x * pw.x; w[5] = ns.y * pw.y; w[6] = ns.z * pw.z; w[7] = ns.w * pw.w;
  }

  float vv[9][8];
  float ss[9], dt[9];
#pragma unroll
  for (int n = 0; n < 9; ++n) {
    const float* rp = (n < 8) ? (blocks + (size_t)n * BTD + rowoff)
                              : (partial + rowoff);
    float4 v0 = *(const float4*)(rp + d0);
    float4 v1 = *(const float4*)(rp + 1024 + d0);
    vv[n][0] = v0.x; vv[n][1] = v0.y; vv[n][2] = v0.z; vv[n][3] = v0.w;
    vv[n][4] = v1.x; vv[n][5] = v1.y; vv[n][6] = v1.z; vv[n][7] = v1.w;
    float a = 0.f, c = 0.f;
#pragma unroll
    for (int j = 0; j < 8; ++j) {
      a += vv[n][j] * vv[n][j];
      c += vv[n][j] * w[j];
    }
    ss[n] = a; dt[n] = c;
  }

  __shared__ float red[2][9][4];
  const int lane = t & 63, wv = t >> 6;
#pragma unroll
  for (int n = 0; n < 9; ++n) {
    float a = ss[n], c = dt[n];
#pragma unroll
    for (int off = 32; off > 0; off >>= 1) {
      a += __shfl_down(a, off, 64);
      c += __shfl_down(c, off, 64);
    }
    if (lane == 0) { red[0][n][wv] = a; red[1][n][wv] = c; }
  }
  __syncthreads();
  __shared__ float logit_s[9];
  if (t < 9) {
    float a = red[0][t][0] + red[0][t][1] + red[0][t][2] + red[0][t][3];
    float c = red[1][t][0] + red[1][t][1] + red[1][t][2] + red[1][t][3];
    logit_s[t] = c * rsqrtf(a * (1.0f / (float)DD) + 1e-8f);
  }
  __syncthreads();

  float lg[9], mx = -1e30f;
#pragma unroll
  for (int n = 0; n < 9; ++n) { lg[n] = logit_s[n]; mx = fmaxf(mx, lg[n]); }
  float den = 0.0f;
#pragma unroll
  for (int n = 0; n < 9; ++n) { lg[n] = __expf(lg[n] - mx); den += lg[n]; }
  const float inv = 1.0f / den;

  float h[8] = {0, 0, 0, 0, 0, 0, 0, 0};
#pragma unroll
  for (int n = 0; n < 9; ++n) {
    const float a = lg[n] * inv;
#pragma unroll
    for (int j = 0; j < 8; ++j) h[j] += a * vv[n][j];
  }

  float4 o0 = {h[0], h[1], h[2], h[3]}, o1 = {h[4], h[5], h[6], h[7]};
  *(float4*)(h_out + rowoff + d0) = o0;
  *(float4*)(h_out + rowoff + 1024 + d0) = o1;
  uint2 p0, p1;
  p0.x = (unsigned)f2bf(h[0]) | ((unsigned)f2bf(h[1]) << 16);
  p0.y = (unsigned)f2bf(h[2]) | ((unsigned)f2bf(h[3]) << 16);
  p1.x = (unsigned)f2bf(h[4]) | ((unsigned)f2bf(h[5]) << 16);
  p1.y = (unsigned)f2bf(h[6]) | ((unsigned)f2bf(h[7]) << 16);
  *(uint2*)(h_bf + rowoff + d0) = p0;
  *(uint2*)(h_bf + rowoff + 1024 + d0) = p1;
}

// ---------------------------------------------------------------------------
// Quad-ring bf16 GEMM, full fragment look-ahead + WAVE-PARITY DE-PHASING.
// Roofline (R12 post-mortem, CU LDS BW = 256 B/cyc): per K=32 subtile/CU,
// LDS = 96 KB reads + 32 KB stage-writes ~= 512 cyc; MFMA = 310 cyc.
// All R2-R12 schedules measured 310/(512+310) = 38% because the 8 waves are
// barrier-locked twins: every wave reads, then every wave MFMAs - the two
// pipes alternate CU-wide (serial SUM).  m201's 62% = 310/512 overlap bound.
// Fix: ODD waves run {MFMA(t); reads(t+1)}, EVEN waves {reads(t+1); MFMA(t)}
// (wave-uniform branch, no divergence).  On each SIMD (one even + one odd
// wave) the odd wave's register-only MFMAs feed the matrix pipe immediately
// after barrier-exit while the even wave's ds_reads drain on the LDS pipe;
// roles swap mid-interval.  sched_barrier(0) between the two sections in
// each branch stops the compiler re-merging the shape.
// Everything else unchanged+verified: ring-4 legality, rowpair-XOR LDS
// layout (0 conflicts), pre-swizzled global source, counted vmcnt (never 0
// mid-loop), 2D XCD supertile, 2 waves/SIMD.
// EPI=0: C = gelu(A@B) -> bf16.  EPI=1: C = A@B + addend -> fp32.
template <int BN, int WM, int WN, int SBY, int SBX, int MCX, int EPI>
__global__ __launch_bounds__(512, 2) void gemmR(
    const ushort_t* __restrict__ A, const ushort_t* __restrict__ BT,
    const int K, const int N, ushort_t* __restrict__ Cb,
    const float* __restrict__ addend, float* __restrict__ Cf) {
  constexpr int MFR = 256 / WM / 16;   // m-frags per wave
  constexpr int NFR = BN / WN / 16;    // n-frags per wave
  constexpr int AS = 16384;            // A sub-tile bytes (256 x 32 x 2B)
  constexpr int BS = BN * 64;          // B sub-tile bytes
  constexpr int RS = AS + BS;          // ring stride
  constexpr int LA = 2;                // A stage batches (8192 B each, 512 thr)
  constexpr int LBN = BS / 8192;       // B stage batches (2 | 1)
  constexpr int LT = LA + LBN;         // loads/thread/sub-tile (4 | 3)

  __shared__ __align__(16) char lds[4 * RS];

  const int t = threadIdx.x;
  const int lane = t & 63, wv = t >> 6;
  const int fr = lane & 15, kslot = lane >> 4;
  const int WRow = (wv / WN) * (256 / WM);
  const int WCol = (wv % WN) * (BN / WN);
  const bool mfma_first = (wv & 1);    // parity de-phasing

  // 2D XCD supertile
  const int wg = blockIdx.x;
  const int xcd = wg & 7, local = wg >> 3;
  const int by = (xcd / MCX) * SBY + local / SBX;
  const int bx = (xcd % MCX) * SBX + local % SBX;
  const int row0 = by * 256, col0 = bx * BN;

  // staging sources: thread covers LDS bytes o = j*8192 + t*16 (linear dest);
  // global element = inverse of the rowpair+XOR layout.
  const ushort_t* ga[LA];
  const ushort_t* gb[LBN];
#pragma unroll
  for (int j = 0; j < LA; ++j) {
    const int o = j * 8192 + t * 16;
    const int rp = o >> 7;
    const int iX = (o & 127) ^ ((rp & 7) << 4);
    ga[j] = A + (size_t)(row0 + rp * 2 + (iX >> 6)) * K + ((iX & 63) >> 1);
  }
#pragma unroll
  for (int j = 0; j < LBN; ++j) {
    const int o = j * 8192 + t * 16;
    const int rp = o >> 7;
    const int iX = (o & 127) ^ ((rp & 7) << 4);
    gb[j] = BT + (size_t)(col0 + rp * 2 + (iX >> 6)) * K + ((iX & 63) >> 1);
  }

#define STAGE(QQ, KT)                                                          \
  {                                                                            \
    _Pragma("unroll") for (int j = 0; j < LA; ++j)                             \
      ASYNC_COPY16(ga[j] + (size_t)(KT) * 32,                                  \
                   lds + (QQ)*RS + j * 8192 + t * 16);                         \
    _Pragma("unroll") for (int j = 0; j < LBN; ++j)                            \
      ASYNC_COPY16(gb[j] + (size_t)(KT) * 32,                                  \
                   lds + (QQ)*RS + AS + j * 8192 + t * 16);                    \
  }

  // fragment read offsets: row r = W{Row,Col}+m*16+fr, k = kslot*8..+8:
  // byte = (r>>1)*128 + ((((r&1)<<6)|(kslot<<4)) ^ (((r>>1)&7)<<4));
  // rp&7 is m-independent (m*16 rows = 8 rowpairs).
  const int arp0 = (WRow + fr) >> 1;
  const int aoff =
      arp0 * 128 + (((((fr & 1) << 6) | (kslot << 4))) ^ ((arp0 & 7) << 4));
  const int brp0 = (WCol + fr) >> 1;
  const int boff = AS + brp0 * 128 +
                   (((((fr & 1) << 6) | (kslot << 4))) ^ ((brp0 & 7) << 4));

  // two full fragment sets: set(t) consumed while set(t+1) is read
  bf16x8 a0[MFR], b0[NFR], a1[MFR], b1[NFR];

#define READF(AX, BX, Lb)                                                      \
  {                                                                            \
    _Pragma("unroll") for (int m = 0; m < MFR; ++m)                            \
      AX[m] = *(const bf16x8*)((Lb) + aoff + m * 1024);                        \
    _Pragma("unroll") for (int n = 0; n < NFR; ++n)                            \
      BX[n] = *(const bf16x8*)((Lb) + boff + n * 1024);                        \
  }

  f32x4 acc[MFR][NFR];
#pragma unroll
  for (int m = 0; m < MFR; ++m)
#pragma unroll
    for (int n = 0; n < NFR; ++n) {
      f32x4 z = {0.f, 0.f, 0.f, 0.f};
      acc[m][n] = z;
    }

#define MFMA_(a, b, c) __builtin_amdgcn_mfma_f32_16x16x32_bf16(a, b, c, 0, 0, 0)
#define MFMA_CLUSTER(AC, BC)                                                   \
  {                                                                            \
    __builtin_amdgcn_s_setprio(1);                                             \
    _Pragma("unroll") for (int m = 0; m < MFR; ++m)                            \
      _Pragma("unroll") for (int n = 0; n < NFR; ++n)                          \
        acc[m][n] = MFMA_(AC[m], BC[n], acc[m][n]);                            \
    __builtin_amdgcn_s_setprio(0);                                             \
  }

  // Interval: stage(t+3) [VMEM issue only]; then parity-ordered
  // {reads(t+1) | MFMA(t)}; counted vmcnt; barrier.
#define INTERVAL(QQ, KT, AC, BC, AN, BNX)                                      \
  {                                                                            \
    if ((KT) + 3 < NT) STAGE(((QQ) + 3) & 3, (KT) + 3);                        \
    const char* Ln = lds + (((QQ) + 1) & 3) * RS;                              \
    if (mfma_first) {                                                          \
      MFMA_CLUSTER(AC, BC);                                                    \
      __builtin_amdgcn_sched_barrier(0);                                       \
      if ((KT) + 1 < NT) READF(AN, BNX, Ln);                                   \
    } else {                                                                   \
      if ((KT) + 1 < NT) READF(AN, BNX, Ln);                                   \
      __builtin_amdgcn_sched_barrier(0);                                       \
      MFMA_CLUSTER(AC, BC);                                                    \
    }                                                                          \
    if ((KT) + 3 < NT) wait_vmcnt<LT>(); else wait_vmcnt<0>();                 \
    __builtin_amdgcn_s_barrier();                                              \
  }

  const int NT = K >> 5;  // sub-tiles of K=32 (64 or 256; multiple of 4)

  // prologue: stage 0,1,2; wait 0,1 landed (buf2 in flight); read frags(0).
  STAGE(0, 0);
  STAGE(1, 1);
  STAGE(2, 2);
  wait_vmcnt<LT>();
  __builtin_amdgcn_s_barrier();
  READF(a0, b0, (const char*)lds);

  for (int t0 = 0; t0 < NT; t0 += 4) {
    INTERVAL(0, t0 + 0, a0, b0, a1, b1);
    INTERVAL(1, t0 + 1, a1, b1, a0, b0);
    INTERVAL(2, t0 + 2, a0, b0, a1, b1);
    INTERVAL(3, t0 + 3, a1, b1, a0, b0);
  }

  const int r4 = kslot * 4;
#pragma unroll
  for (int m = 0; m < MFR; ++m) {
    const int grow = row0 + WRow + m * 16 + r4;
#pragma unroll
    for (int n = 0; n < NFR; ++n) {
      const int gcol = col0 + WCol + n * 16 + fr;
#pragma unroll
      for (int r = 0; r < 4; ++r) {
        const float v = acc[m][n][r];
        const size_t idx = (size_t)(grow + r) * N + gcol;
        if (EPI == 0) {
          Cb[idx] = f2bf(gelu_tanh(v));
        } else {
          Cf[idx] = v + addend[idx];
        }
      }
    }
  }
#undef INTERVAL
#undef MFMA_CLUSTER
#undef MFMA_
#undef READF
#undef STAGE
}

// ---------------------------------------------------------------------------
extern "C" void kernel_launch(void* const* d_in, const int* in_sizes, int n_in,
                              void* d_out, int out_size, void* d_ws,
                              size_t ws_size, hipStream_t stream) {
  const float* blocks = (const float*)d_in[0];
  const float* partial = (const float*)d_in[1];
  const float* proj_w = (const float*)d_in[2];
  const float* norm_scale = (const float*)d_in[3];
  const float* w1 = (const float*)d_in[4];
  const float* w2 = (const float*)d_in[5];

  float* out = (float*)d_out;
  float* h_out = out;                 // [B,T,D] fp32
  float* new_partial = out + BTD;     // [B,T,D] fp32

  char* ws = (char*)d_ws;
  ushort_t* h_bf = (ushort_t*)ws;                                        // 16 MB
  ushort_t* w1T = (ushort_t*)(ws + (size_t)16777216);                    // 32 MB (F x D)
  ushort_t* w2T = (ushort_t*)(ws + (size_t)16777216 + 33554432);         // 32 MB (D x F)
  ushort_t* act = (ushort_t*)(ws + (size_t)16777216 + 2 * 33554432ull);  // 64 MB (M x F)

  // weight convert + transpose to (N x K) bf16
  transpose_conv<<<dim3(FF / 32, DD / 32), 256, 0, stream>>>(w1, w1T, DD, FF);
  transpose_conv<<<dim3(DD / 32, FF / 32), 256, 0, stream>>>(w2, w2T, FF, DD);

  // fused attention -> h (fp32 out) + h (bf16 for GEMM)
  attn_fuse<<<MM, 256, 0, stream>>>(blocks, partial, proj_w, norm_scale, h_out,
                                    h_bf);

  // FFN: act = gelu(h @ W1) ; new_partial = act @ W2 + partial
  // GEMM1: 256x256 tile, 8 waves 2Mx4N (wave 128x64), grid 16x32=512,
  //        XCD supertile 8x8 (macro 2x4).
  gemmR<256, 2, 4, 8, 8, 4, 0><<<512, 512, 0, stream>>>(
      h_bf, w1T, DD, FF, act, nullptr, nullptr);
  // GEMM2: 256x128 tile, 8 waves 4Mx2N (wave 64x64), grid 16x16=256,
  //        XCD supertile 4x8 (macro 4x2).
  gemmR<128, 4, 2, 4, 8, 2, 1><<<256, 512, 0, stream>>>(
      act, w2T, FF, DD, nullptr, partial, new_partial);
}

// Round 14
// 391.474 us; speedup vs baseline: 4.1970x; 4.1970x over previous
//
#include <hip/hip_runtime.h>

typedef unsigned short ushort_t;
typedef __bf16 bf16x8 __attribute__((ext_vector_type(8)));
typedef float f32x4 __attribute__((ext_vector_type(4)));

// sizes (fixed by the problem)
#define NB 8
#define BB 2
#define TT 2048
#define DD 2048
#define FF 8192
#define MM (BB * TT)          // 4096 rows
#define BTD ((size_t)BB * TT * DD)   // 8388608

__device__ __forceinline__ unsigned short f2bf(float f) {
  unsigned int u = __float_as_uint(f);
  u += 0x7FFFu + ((u >> 16) & 1u);
  return (unsigned short)(u >> 16);
}

__device__ __forceinline__ float gelu_tanh(float x) {
  float u = 0.7978845608028654f * (x + 0.044715f * x * x * x);
  float e = __expf(2.0f * u);
  float th = 1.0f - 2.0f / (e + 1.0f);   // robust tanh(u), e=inf -> 1
  return 0.5f * x * (1.0f + th);
}

template <int N>
__device__ __forceinline__ void wait_vmcnt() {
  if constexpr (N == 0) asm volatile("s_waitcnt vmcnt(0)" ::: "memory");
  else if constexpr (N == 3) asm volatile("s_waitcnt vmcnt(3)" ::: "memory");
  else if constexpr (N == 4) asm volatile("s_waitcnt vmcnt(4)" ::: "memory");
  else if constexpr (N == 6) asm volatile("s_waitcnt vmcnt(6)" ::: "memory");
  else if constexpr (N == 8) asm volatile("s_waitcnt vmcnt(8)" ::: "memory");
}

#define ASYNC_COPY16(gp, lp)                                                   \
  __builtin_amdgcn_global_load_lds(                                            \
      (__attribute__((address_space(1))) void*)(gp),                           \
      (__attribute__((address_space(3))) void*)(lp), 16, 0, 0)

// ---------------------------------------------------------------------------
// fp32 (R x C) -> bf16 transposed (C x R).  float4 in, ushort4 out (G13).
__global__ __launch_bounds__(256) void transpose_conv(
    const float* __restrict__ in, ushort_t* __restrict__ out, int R, int C) {
  __shared__ float tile[32][33];
  const int tx = threadIdx.x & 7;   // 8 x float4 = 32 cols
  const int ty = threadIdx.x >> 3;  // 32 rows
  const int r0 = blockIdx.y * 32, c0 = blockIdx.x * 32;
  float4 v = *(const float4*)(in + (size_t)(r0 + ty) * C + c0 + tx * 4);
  tile[ty][tx * 4 + 0] = v.x;
  tile[ty][tx * 4 + 1] = v.y;
  tile[ty][tx * 4 + 2] = v.z;
  tile[ty][tx * 4 + 3] = v.w;
  __syncthreads();
  ushort4 o;
  o.x = f2bf(tile[tx * 4 + 0][ty]);
  o.y = f2bf(tile[tx * 4 + 1][ty]);
  o.z = f2bf(tile[tx * 4 + 2][ty]);
  o.w = f2bf(tile[tx * 4 + 3][ty]);
  *(ushort4*)(out + (size_t)(c0 + ty) * R + r0 + tx * 4) = o;
}

// ---------------------------------------------------------------------------
// Fused block-attention: ONE PASS over V (V rows held in registers).
__global__ __launch_bounds__(256) void attn_fuse(
    const float* __restrict__ blocks, const float* __restrict__ partial,
    const float* __restrict__ proj_w, const float* __restrict__ norm_scale,
    float* __restrict__ h_out, ushort_t* __restrict__ h_bf) {
  const int t = threadIdx.x;
  const int bt = blockIdx.x;
  const size_t rowoff = (size_t)bt * DD;
  const int d0 = t * 4;

  float w[8];
  {
    float4 ns = *(const float4*)(norm_scale + d0);
    float4 pw = *(const float4*)(proj_w + d0);
    w[0] = ns.x * pw.x; w[1] = ns.y * pw.y; w[2] = ns.z * pw.z; w[3] = ns.w * pw.w;
    ns = *(const float4*)(norm_scale + 1024 + d0);
    pw = *(const float4*)(proj_w + 1024 + d0);
    w[4] = ns.x * pw.x; w[5] = ns.y * pw.y; w[6] = ns.z * pw.z; w[7] = ns.w * pw.w;
  }

  float vv[9][8];
  float ss[9], dt[9];
#pragma unroll
  for (int n = 0; n < 9; ++n) {
    const float* rp = (n < 8) ? (blocks + (size_t)n * BTD + rowoff)
                              : (partial + rowoff);
    float4 v0 = *(const float4*)(rp + d0);
    float4 v1 = *(const float4*)(rp + 1024 + d0);
    vv[n][0] = v0.x; vv[n][1] = v0.y; vv[n][2] = v0.z; vv[n][3] = v0.w;
    vv[n][4] = v1.x; vv[n][5] = v1.y; vv[n][6] = v1.z; vv[n][7] = v1.w;
    float a = 0.f, c = 0.f;
#pragma unroll
    for (int j = 0; j < 8; ++j) {
      a += vv[n][j] * vv[n][j];
      c += vv[n][j] * w[j];
    }
    ss[n] = a; dt[n] = c;
  }

  __shared__ float red[2][9][4];
  const int lane = t & 63, wv = t >> 6;
#pragma unroll
  for (int n = 0; n < 9; ++n) {
    float a = ss[n], c = dt[n];
#pragma unroll
    for (int off = 32; off > 0; off >>= 1) {
      a += __shfl_down(a, off, 64);
      c += __shfl_down(c, off, 64);
    }
    if (lane == 0) { red[0][n][wv] = a; red[1][n][wv] = c; }
  }
  __syncthreads();
  __shared__ float logit_s[9];
  if (t < 9) {
    float a = red[0][t][0] + red[0][t][1] + red[0][t][2] + red[0][t][3];
    float c = red[1][t][0] + red[1][t][1] + red[1][t][2] + red[1][t][3];
    logit_s[t] = c * rsqrtf(a * (1.0f / (float)DD) + 1e-8f);
  }
  __syncthreads();

  float lg[9], mx = -1e30f;
#pragma unroll
  for (int n = 0; n < 9; ++n) { lg[n] = logit_s[n]; mx = fmaxf(mx, lg[n]); }
  float den = 0.0f;
#pragma unroll
  for (int n = 0; n < 9; ++n) { lg[n] = __expf(lg[n] - mx); den += lg[n]; }
  const float inv = 1.0f / den;

  float h[8] = {0, 0, 0, 0, 0, 0, 0, 0};
#pragma unroll
  for (int n = 0; n < 9; ++n) {
    const float a = lg[n] * inv;
#pragma unroll
    for (int j = 0; j < 8; ++j) h[j] += a * vv[n][j];
  }

  float4 o0 = {h[0], h[1], h[2], h[3]}, o1 = {h[4], h[5], h[6], h[7]};
  *(float4*)(h_out + rowoff + d0) = o0;
  *(float4*)(h_out + rowoff + 1024 + d0) = o1;
  uint2 p0, p1;
  p0.x = (unsigned)f2bf(h[0]) | ((unsigned)f2bf(h[1]) << 16);
  p0.y = (unsigned)f2bf(h[2]) | ((unsigned)f2bf(h[3]) << 16);
  p1.x = (unsigned)f2bf(h[4]) | ((unsigned)f2bf(h[5]) << 16);
  p1.y = (unsigned)f2bf(h[6]) | ((unsigned)f2bf(h[7]) << 16);
  *(uint2*)(h_bf + rowoff + d0) = p0;
  *(uint2*)(h_bf + rowoff + 1024 + d0) = p1;
}

// ---------------------------------------------------------------------------
// Quad-ring bf16 GEMM (R7 configuration — best of session, reverted to
// verbatim).  BM=256, BK=32 sub-tiles, 4 rotating LDS buffers, ONE barrier
// per sub-tile.  8 waves (WM x WN), per-wave tile (256/WM) x (BN/WN).
// Schedule per sub-tile t:
//   wait vmcnt(L*min(2,NT-1-t))  // tile t landed; t+1,t+2 in flight
//   s_barrier                    // t visible to all; readers of t-1 done
//   stage(t+3) -> buf[(t+3)&3]   // == buf[(t-1)&3], race-free by barrier
//   ds_read 12|8 frags; 32|16 MFMA (compiler-placed partial lgkm waits)
// Session verdict: 13 structurally distinct schedules (2-barrier, 4/8-phase
// counted-vmcnt, quad-ring, B-/dual-operand look-ahead, sched_barrier pin,
// wave-parity) all land 858-898 TF / 33-39% MfmaUtil — the documented
// m97-class plain-HIP ceiling for this staging+LDS+MFMA invariant.  This
// config is the fastest measured instance (898 TF, VGPR 88, 0 conflicts).
// LDS rowpair-packed XOR layout (conflict-free); pre-swizzled global source;
// 2D XCD supertile (FETCH 270->147 MB).
// EPI=0: C = gelu(A@B) -> bf16.  EPI=1: C = A@B + addend -> fp32.
template <int BN, int WM, int WN, int SBY, int SBX, int MCX, int EPI>
__global__ __launch_bounds__(512, 2) void gemmQ(
    const ushort_t* __restrict__ A, const ushort_t* __restrict__ BT,
    const int K, const int N, ushort_t* __restrict__ Cb,
    const float* __restrict__ addend, float* __restrict__ Cf) {
  constexpr int MFR = 256 / WM / 16;   // m-frags per wave
  constexpr int NFR = BN / WN / 16;    // n-frags per wave
  constexpr int AS = 16384;            // A sub-tile bytes (256 x 32 x 2B)
  constexpr int BS = BN * 64;          // B sub-tile bytes
  constexpr int RS = AS + BS;          // ring stride
  constexpr int LB = BS / 8192;        // B loads/thread (2 | 1)
  constexpr int LT = 2 + LB;           // loads/thread/sub-tile

  __shared__ __align__(16) char lds[4 * RS];

  const int t = threadIdx.x;
  const int lane = t & 63, wv = t >> 6;
  const int fr = lane & 15, kslot = lane >> 4;
  const int WRow = (wv / WN) * (256 / WM);
  const int WCol = (wv % WN) * (BN / WN);

  // 2D XCD supertile
  const int wg = blockIdx.x;
  const int xcd = wg & 7, local = wg >> 3;
  const int by = (xcd / MCX) * SBY + local / SBX;
  const int bx = (xcd % MCX) * SBX + local % SBX;
  const int row0 = by * 256, col0 = bx * BN;

  // staging sources: thread covers LDS bytes o = j*8192 + t*16 (linear dest);
  // global element = inverse of the rowpair+XOR layout.
  const ushort_t* ga[2];
  const ushort_t* gb[LB];
#pragma unroll
  for (int j = 0; j < 2; ++j) {
    const int o = j * 8192 + t * 16;
    const int rp = o >> 7;
    const int iX = (o & 127) ^ ((rp & 7) << 4);
    ga[j] = A + (size_t)(row0 + rp * 2 + (iX >> 6)) * K + ((iX & 63) >> 1);
  }
#pragma unroll
  for (int j = 0; j < LB; ++j) {
    const int o = j * 8192 + t * 16;
    const int rp = o >> 7;
    const int iX = (o & 127) ^ ((rp & 7) << 4);
    gb[j] = BT + (size_t)(col0 + rp * 2 + (iX >> 6)) * K + ((iX & 63) >> 1);
  }

#define STAGE(QQ, KT)                                                          \
  {                                                                            \
    ASYNC_COPY16(ga[0] + (size_t)(KT) * 32, lds + (QQ)*RS + t * 16);           \
    ASYNC_COPY16(ga[1] + (size_t)(KT) * 32, lds + (QQ)*RS + 8192 + t * 16);    \
    ASYNC_COPY16(gb[0] + (size_t)(KT) * 32, lds + (QQ)*RS + AS + t * 16);      \
    if constexpr (LB == 2)                                                     \
      ASYNC_COPY16(gb[1] + (size_t)(KT) * 32,                                  \
                   lds + (QQ)*RS + AS + 8192 + t * 16);                        \
  }

  // fragment read offsets: row r = W{Row,Col}+m*16+fr, k = kslot*8..+8:
  // byte = (r>>1)*128 + ((((r&1)<<6)|(kslot<<4)) ^ (((r>>1)&7)<<4));
  // rp&7 is m-independent (m*16 rows = m*8 rowpairs, multiple of 8).
  const int arp0 = (WRow + fr) >> 1;
  const int aoff =
      arp0 * 128 + (((((fr & 1) << 6) | (kslot << 4))) ^ ((arp0 & 7) << 4));
  const int brp0 = (WCol + fr) >> 1;
  const int boff = AS + brp0 * 128 +
                   (((((fr & 1) << 6) | (kslot << 4))) ^ ((brp0 & 7) << 4));

  f32x4 acc[MFR][NFR];
#pragma unroll
  for (int m = 0; m < MFR; ++m)
#pragma unroll
    for (int n = 0; n < NFR; ++n) {
      f32x4 z = {0.f, 0.f, 0.f, 0.f};
      acc[m][n] = z;
    }

#define MFMA_(a, b, c) __builtin_amdgcn_mfma_f32_16x16x32_bf16(a, b, c, 0, 0, 0)

  const int NT = K >> 5;  // sub-tiles of K=32 (64 or 256; multiple of 4)

  STAGE(0, 0);
  STAGE(1, 1);
  STAGE(2, 2);

  for (int t0 = 0; t0 < NT; t0 += 4) {
#pragma unroll
    for (int q = 0; q < 4; ++q) {
      const int kt = t0 + q;
      const int rem = NT - 1 - kt;
      if (rem >= 2) wait_vmcnt<2 * LT>();
      else if (rem == 1) wait_vmcnt<LT>();
      else wait_vmcnt<0>();
      __builtin_amdgcn_s_barrier();
      if (kt + 3 < NT) STAGE((q + 3) & 3, kt + 3);
      const char* Lq = lds + q * RS;
      bf16x8 af[MFR], bfv[NFR];
#pragma unroll
      for (int m = 0; m < MFR; ++m)
        af[m] = *(const bf16x8*)(Lq + aoff + m * 1024);
#pragma unroll
      for (int n = 0; n < NFR; ++n)
        bfv[n] = *(const bf16x8*)(Lq + boff + n * 1024);
      __builtin_amdgcn_s_setprio(1);
#pragma unroll
      for (int m = 0; m < MFR; ++m)
#pragma unroll
        for (int n = 0; n < NFR; ++n)
          acc[m][n] = MFMA_(af[m], bfv[n], acc[m][n]);
      __builtin_amdgcn_s_setprio(0);
    }
  }

  const int r4 = kslot * 4;
#pragma unroll
  for (int m = 0; m < MFR; ++m) {
    const int grow = row0 + WRow + m * 16 + r4;
#pragma unroll
    for (int n = 0; n < NFR; ++n) {
      const int gcol = col0 + WCol + n * 16 + fr;
#pragma unroll
      for (int r = 0; r < 4; ++r) {
        const float v = acc[m][n][r];
        const size_t idx = (size_t)(grow + r) * N + gcol;
        if (EPI == 0) {
          Cb[idx] = f2bf(gelu_tanh(v));
        } else {
          Cf[idx] = v + addend[idx];
        }
      }
    }
  }
#undef MFMA_
#undef STAGE
}

// ---------------------------------------------------------------------------
extern "C" void kernel_launch(void* const* d_in, const int* in_sizes, int n_in,
                              void* d_out, int out_size, void* d_ws,
                              size_t ws_size, hipStream_t stream) {
  const float* blocks = (const float*)d_in[0];
  const float* partial = (const float*)d_in[1];
  const float* proj_w = (const float*)d_in[2];
  const float* norm_scale = (const float*)d_in[3];
  const float* w1 = (const float*)d_in[4];
  const float* w2 = (const float*)d_in[5];

  float* out = (float*)d_out;
  float* h_out = out;                 // [B,T,D] fp32
  float* new_partial = out + BTD;     // [B,T,D] fp32

  char* ws = (char*)d_ws;
  ushort_t* h_bf = (ushort_t*)ws;                                        // 16 MB
  ushort_t* w1T = (ushort_t*)(ws + (size_t)16777216);                    // 32 MB (F x D)
  ushort_t* w2T = (ushort_t*)(ws + (size_t)16777216 + 33554432);         // 32 MB (D x F)
  ushort_t* act = (ushort_t*)(ws + (size_t)16777216 + 2 * 33554432ull);  // 64 MB (M x F)

  // weight convert + transpose to (N x K) bf16
  transpose_conv<<<dim3(FF / 32, DD / 32), 256, 0, stream>>>(w1, w1T, DD, FF);
  transpose_conv<<<dim3(DD / 32, FF / 32), 256, 0, stream>>>(w2, w2T, FF, DD);

  // fused attention -> h (fp32 out) + h (bf16 for GEMM)
  attn_fuse<<<MM, 256, 0, stream>>>(blocks, partial, proj_w, norm_scale, h_out,
                                    h_bf);

  // FFN: act = gelu(h @ W1) ; new_partial = act @ W2 + partial
  // GEMM1: 256x256 tile, waves 2Mx4N (wave 128x64), grid 16x32=512,
  //        supertile 8x8 per XCD (macro 2x4).
  gemmQ<256, 2, 4, 8, 8, 4, 0><<<512, 512, 0, stream>>>(
      h_bf, w1T, DD, FF, act, nullptr, nullptr);
  // GEMM2: 256x128 tile, waves 4Mx2N (wave 64x64), grid 16x16=256,
  //        supertile 4x8 per XCD (macro 4x2).
  gemmQ<128, 4, 2, 4, 8, 2, 1><<<256, 512, 0, stream>>>(
      act, w2T, FF, DD, nullptr, partial, new_partial);
}